// Round 10
// baseline (290.337 us; speedup 1.0000x reference)
//
#include <hip/hip_runtime.h>
#include <hip/hip_cooperative_groups.h>
#include <math.h>

// ---------------------------------------------------------------------------
// GCN: 3x GCNConv (linear) -> mean pool -> linear -> sigmoid.
// Linear-collapse identity (absmax 0.0 through R9):
//   h3 @ lin_w = A(A(A(X u) + s2) + s1) + s0,  u = W1W2W3 lin_w.
// R9 lesson: occupancy fix worked; remaining time = structural (scatter
// recomputes hist K1 already did; 5 dependent small dispatches at the tail).
// R10: hist also emits per-block local scan (Mloc); scanA emits cross-block
// prefix (Mpre) separately -> scatter just loads its tables. Tail 5 kernels
// merged into ONE cooperative kernel with grid.sync() (4 dispatches total).
// ---------------------------------------------------------------------------

#define SHIFT      8
#define BSZ        256         // nodes per bucket = 1<<SHIFT
#define NB_SCAT    256         // blocks for hist/scatter phases
#define B_SCAT     1024        // threads for hist/scatter
#define B_MEGA     1024        // threads for mega kernel
#define ROWMASK    0x1FFFFu    // 17 bits for row id (n < 131072)
#define PSLOTS     64          // LDS pool slots in pool phase
#define MAXNB      2048        // scan capacity guard

namespace cg = cooperative_groups;

// ---- K1: histogram + in-block scan (Mcnt, Mloc) + coeffs + zero sums ----
__global__ void hist_kernel(const int* __restrict__ col, int E, int tile, int nbuck,
                            unsigned* __restrict__ Mcnt, unsigned* __restrict__ Mloc,
                            const float* __restrict__ W1, const float* __restrict__ b1,
                            const float* __restrict__ W2, const float* __restrict__ b2,
                            const float* __restrict__ W3, const float* __restrict__ b3,
                            const float* __restrict__ lin_w, const float* __restrict__ lin_b,
                            float* __restrict__ coeff,
                            float* __restrict__ sums, float* __restrict__ cnt, int ngraphs) {
    extern __shared__ unsigned h[];
    __shared__ unsigned tsum[B_SCAT];
    __shared__ float w3l[16], w2l[16];
    int t = threadIdx.x;
    for (int i = t; i < nbuck; i += blockDim.x) h[i] = 0;
    if (blockIdx.x == 0) {
        for (int i = t; i < ngraphs; i += blockDim.x) { sums[i] = 0.f; cnt[i] = 0.f; }
        if (t < 16) {
            float s = 0.f;
            for (int j = 0; j < 16; ++j) s += W3[t * 16 + j] * lin_w[j];
            w3l[t] = s;
        }
    }
    __syncthreads();
    if (blockIdx.x == 0 && t < 16) {
        float s = 0.f;
        for (int j = 0; j < 16; ++j) s += W2[t * 16 + j] * w3l[j];
        w2l[t] = s;
    }
    __syncthreads();
    if (blockIdx.x == 0) {
        if (t < 4) {
            float s = 0.f;
            for (int j = 0; j < 16; ++j) s += W1[t * 16 + j] * w2l[j];
            coeff[t] = s;
        } else if (t == 4) {
            float s = 0.f;
            for (int j = 0; j < 16; ++j) s += b1[j] * w2l[j];
            coeff[4] = s;
        } else if (t == 5) {
            float s = 0.f;
            for (int j = 0; j < 16; ++j) s += b2[j] * w3l[j];
            coeff[5] = s;
        } else if (t == 6) {
            float s = 0.f;
            for (int j = 0; j < 16; ++j) s += b3[j] * lin_w[j];
            coeff[6] = s;
        } else if (t == 7) {
            coeff[7] = lin_b[0];
        }
    }
    // histogram of this block's tile
    int b = blockIdx.x;
    int s = b * tile, e = min(s + tile, E);          // s multiple of 4
    if (s < e) {
        int nq = (e - s) >> 2;
        const int4* c4 = (const int4*)(col + s);
        for (int q = t; q < nq; q += blockDim.x) {
            int4 c = c4[q];
            atomicAdd(&h[((unsigned)c.x) >> SHIFT], 1u);
            atomicAdd(&h[((unsigned)c.y) >> SHIFT], 1u);
            atomicAdd(&h[((unsigned)c.z) >> SHIFT], 1u);
            atomicAdd(&h[((unsigned)c.w) >> SHIFT], 1u);
        }
        for (int k = s + (nq << 2) + t; k < e; k += blockDim.x)
            atomicAdd(&h[((unsigned)col[k]) >> SHIFT], 1u);
    }
    __syncthreads();
    // in-block exclusive scan of h -> Mloc; counts -> Mcnt
    const int C = MAXNB / B_SCAT;            // 2 elems/thread
    unsigned lv[C];
    unsigned run = 0;
    for (int k = 0; k < C; ++k) {
        int i = t * C + k;
        unsigned x = (i < nbuck) ? h[i] : 0u;
        lv[k] = run; run += x;
    }
    tsum[t] = run;
    __syncthreads();
    for (int off = 1; off < B_SCAT; off <<= 1) {
        unsigned u = (t >= off) ? tsum[t - off] : 0u;
        __syncthreads();
        tsum[t] += u;
        __syncthreads();
    }
    unsigned ex = (t == 0) ? 0u : tsum[t - 1];
    for (int k = 0; k < C; ++k) {
        int i = t * C + k;
        if (i < nbuck) {
            Mcnt[(size_t)b * nbuck + i] = h[i];
            Mloc[(size_t)b * nbuck + i] = ex + lv[k];
        }
    }
}

// ---- K2: per-bin exclusive scan over block counts -> Mpre, binTotal ----
__global__ void scanA_kernel(const unsigned* __restrict__ Mcnt, unsigned* __restrict__ Mpre,
                             unsigned* __restrict__ binTotal, int nbuck) {
    __shared__ unsigned sc[NB_SCAT];
    int b = blockIdx.x;
    int t = threadIdx.x;
    unsigned v = Mcnt[(size_t)t * nbuck + b];
    sc[t] = v;
    __syncthreads();
    for (int off = 1; off < NB_SCAT; off <<= 1) {
        unsigned u = (t >= off) ? sc[t - off] : 0u;
        __syncthreads();
        sc[t] += u;
        __syncthreads();
    }
    Mpre[(size_t)t * nbuck + b] = sc[t] - v;     // exclusive within bin
    if (t == NB_SCAT - 1) binTotal[b] = sc[t];
}

// ---- K3: scatter; tables preloaded, only binTotal scan in-block ----
// pack: row(17b) | col_low(8b)<<17
__global__ void scatter_kernel(const int* __restrict__ row, const int* __restrict__ col,
                               int E, int tile, int nbuck,
                               const unsigned* __restrict__ Mcnt,
                               const unsigned* __restrict__ Mloc,
                               const unsigned* __restrict__ Mpre,
                               const unsigned* __restrict__ binTotal,
                               unsigned* __restrict__ bstart,
                               unsigned* __restrict__ out) {
    extern __shared__ unsigned lds[];
    unsigned* hA    = lds;                   // nbuck  local counts
    unsigned* lofs  = lds + nbuck;           // nbuck  local exclusive offsets
    unsigned* lcur  = lds + 2 * nbuck;       // nbuck  placement cursors
    unsigned* gbase = lds + 3 * nbuck;       // nbuck  global run starts (this block)
    unsigned* tsum  = lds + 4 * nbuck;       // B_SCAT scan workspace
    unsigned* stage = lds + 4 * nbuck + B_SCAT; // tile staged packed words
    int t = threadIdx.x, j = blockIdx.x;
    // load local tables
    for (int i = t; i < nbuck; i += blockDim.x) {
        unsigned c = Mcnt[(size_t)j * nbuck + i];
        unsigned l = Mloc[(size_t)j * nbuck + i];
        hA[i] = c; lofs[i] = l; lcur[i] = l;
    }
    // binTotal exclusive scan -> gbase (+ bstart publish from block 0)
    const int C = MAXNB / B_SCAT;            // 2 elems/thread
    unsigned lv[C];
    unsigned run = 0;
    for (int k = 0; k < C; ++k) {
        int i = t * C + k;
        unsigned x = (i < nbuck) ? binTotal[i] : 0u;
        lv[k] = run; run += x;
    }
    tsum[t] = run;
    __syncthreads();
    for (int off = 1; off < B_SCAT; off <<= 1) {
        unsigned u = (t >= off) ? tsum[t - off] : 0u;
        __syncthreads();
        tsum[t] += u;
        __syncthreads();
    }
    unsigned ex = (t == 0) ? 0u : tsum[t - 1];
    for (int k = 0; k < C; ++k) {
        int i = t * C + k;
        if (i < nbuck) {
            unsigned bb = ex + lv[k];
            gbase[i] = bb + Mpre[(size_t)j * nbuck + i];
            if (j == 0) bstart[i] = bb;
        }
    }
    if (j == 0 && t == 0) bstart[nbuck] = (unsigned)E;
    __syncthreads();
    // placement into stage (LDS random write)
    int s = j * tile, e = min(s + tile, E);
    if (s < e) {
        int nq = (e - s) >> 2;
        const int4* r4 = (const int4*)(row + s);
        const int4* c4 = (const int4*)(col + s);
        for (int q = t; q < nq; q += blockDim.x) {
            int4 r = r4[q];
            int4 c = c4[q];
            unsigned p0 = atomicAdd(&lcur[((unsigned)c.x) >> SHIFT], 1u);
            unsigned p1 = atomicAdd(&lcur[((unsigned)c.y) >> SHIFT], 1u);
            unsigned p2 = atomicAdd(&lcur[((unsigned)c.z) >> SHIFT], 1u);
            unsigned p3 = atomicAdd(&lcur[((unsigned)c.w) >> SHIFT], 1u);
            stage[p0] = (unsigned)r.x | (((unsigned)c.x & (BSZ - 1)) << 17);
            stage[p1] = (unsigned)r.y | (((unsigned)c.y & (BSZ - 1)) << 17);
            stage[p2] = (unsigned)r.z | (((unsigned)c.z & (BSZ - 1)) << 17);
            stage[p3] = (unsigned)r.w | (((unsigned)c.w & (BSZ - 1)) << 17);
        }
        for (int k = s + (nq << 2) + t; k < e; k += blockDim.x) {
            unsigned c = (unsigned)col[k];
            unsigned pos = atomicAdd(&lcur[c >> SHIFT], 1u);
            stage[pos] = (unsigned)row[k] | ((c & (BSZ - 1)) << 17);
        }
    }
    __syncthreads();
    // flush: per wave per bucket, consecutive lanes -> consecutive addresses
    int wid = t >> 6, lane = t & 63, nw = blockDim.x >> 6;
    for (int b = wid; b < nbuck; b += nw) {
        unsigned cntb = hA[b], lo = lofs[b], go = gbase[b];
        for (unsigned i = lane; i < cntb; i += 64)
            out[go + i] = stage[lo + i];
    }
}

// ---- edge-accumulate helpers ----
__device__ __forceinline__ void accum_gather(const unsigned* __restrict__ buck,
                                             unsigned s, unsigned e,
                                             const float* __restrict__ gin,
                                             float* __restrict__ acc) {
    unsigned sa = (s + 3u) & ~3u;
    if (sa > e) sa = e;
    if (s + threadIdx.x < sa) {
        unsigned w = buck[s + threadIdx.x];
        atomicAdd(&acc[w >> 17], gin[w & ROWMASK]);
    }
    unsigned nq = (e - sa) >> 2;
    const uint4* bq = (const uint4*)(buck + sa);
    for (unsigned q = threadIdx.x; q < nq; q += blockDim.x) {
        uint4 w = bq[q];
        float a0 = gin[w.x & ROWMASK];
        float a1 = gin[w.y & ROWMASK];
        float a2 = gin[w.z & ROWMASK];
        float a3 = gin[w.w & ROWMASK];
        atomicAdd(&acc[w.x >> 17], a0);
        atomicAdd(&acc[w.y >> 17], a1);
        atomicAdd(&acc[w.z >> 17], a2);
        atomicAdd(&acc[w.w >> 17], a3);
    }
    for (unsigned k = sa + (nq << 2) + threadIdx.x; k < e; k += blockDim.x) {
        unsigned w = buck[k];
        atomicAdd(&acc[w >> 17], gin[w & ROWMASK]);
    }
}

__device__ __forceinline__ void accum_count(const unsigned* __restrict__ buck,
                                            unsigned s, unsigned e,
                                            float* __restrict__ acc) {
    unsigned sa = (s + 3u) & ~3u;
    if (sa > e) sa = e;
    if (s + threadIdx.x < sa)
        atomicAdd(&acc[buck[s + threadIdx.x] >> 17], 1.0f);
    unsigned nq = (e - sa) >> 2;
    const uint4* bq = (const uint4*)(buck + sa);
    for (unsigned q = threadIdx.x; q < nq; q += blockDim.x) {
        uint4 w = bq[q];
        atomicAdd(&acc[w.x >> 17], 1.0f);
        atomicAdd(&acc[w.y >> 17], 1.0f);
        atomicAdd(&acc[w.z >> 17], 1.0f);
        atomicAdd(&acc[w.w >> 17], 1.0f);
    }
    for (unsigned k = sa + (nq << 2) + threadIdx.x; k < e; k += blockDim.x)
        atomicAdd(&acc[buck[k] >> 17], 1.0f);
}

// ---- K4 (cooperative): deg+node0 -> g1 -> g2 -> g3+pool -> final ----
__global__ __launch_bounds__(B_MEGA, 8)
void mega_kernel(const unsigned* __restrict__ buck, const unsigned* __restrict__ bstart,
                 const float* __restrict__ x, const float* __restrict__ coeff,
                 const int* __restrict__ batch,
                 float* __restrict__ dinv, float* __restrict__ gA, float* __restrict__ gB,
                 float* __restrict__ sums, float* __restrict__ cnt,
                 float* __restrict__ out, int n, int nbuck, int ngraphs) {
    cg::grid_group grid = cg::this_grid();
    __shared__ float acc[BSZ];
    __shared__ float ls[PSLOTS], lc[PSLOTS];
    __shared__ int bF;
    int b = blockIdx.x, t = threadIdx.x;
    unsigned s = bstart[b], e = bstart[b + 1];
    int node = b * BSZ + t;

    // ---- P0: degree count + node0 epilogue ----
    if (t < BSZ) acc[t] = 0.f;
    __syncthreads();
    accum_count(buck, s, e, acc);
    __syncthreads();
    if (t < BSZ && node < n) {
        float d = rsqrtf(acc[t] + 1.0f);
        dinv[node] = d;
        float4 xv = ((const float4*)x)[node];
        float t0 = xv.x * coeff[0] + xv.y * coeff[1] + xv.z * coeff[2] + xv.w * coeff[3];
        gA[node] = d * t0;
    }
    grid.sync();

    // ---- P1: gather gA -> gB (s2) ----
    if (t < BSZ) acc[t] = 0.f;
    __syncthreads();
    accum_gather(buck, s, e, gA, acc);
    __syncthreads();
    if (t < BSZ && node < n) {
        float d = dinv[node];
        float tt = d * (acc[t] + gA[node]) + coeff[4];
        gB[node] = d * tt;
    }
    grid.sync();

    // ---- P2: gather gB -> gA (s1) ----
    if (t < BSZ) acc[t] = 0.f;
    __syncthreads();
    accum_gather(buck, s, e, gB, acc);
    __syncthreads();
    if (t < BSZ && node < n) {
        float d = dinv[node];
        float tt = d * (acc[t] + gB[node]) + coeff[5];
        gA[node] = d * tt;
    }
    grid.sync();

    // ---- P3: gather gA (s0) + segmented mean-pool (batch sorted) ----
    if (t < BSZ) acc[t] = 0.f;
    for (int i = t; i < PSLOTS; i += blockDim.x) { ls[i] = 0.f; lc[i] = 0.f; }
    if (t == 0) bF = batch[min(b * BSZ, n - 1)];
    __syncthreads();
    accum_gather(buck, s, e, gA, acc);
    __syncthreads();
    if (t < BSZ && node < n) {
        float d = dinv[node];
        float t3 = d * (acc[t] + gA[node]) + coeff[6];
        int rb = batch[node] - bF;               // sorted -> rb >= 0
        if (rb < PSLOTS) {
            atomicAdd(&ls[rb], t3);
            atomicAdd(&lc[rb], 1.0f);
        } else {
            atomicAdd(&sums[bF + rb], t3);
            atomicAdd(&cnt[bF + rb], 1.0f);
        }
    }
    __syncthreads();
    for (int i = t; i < PSLOTS; i += blockDim.x) {
        if (lc[i] != 0.f) {
            atomicAdd(&sums[bF + i], ls[i]);
            atomicAdd(&cnt[bF + i], lc[i]);
        }
    }
    grid.sync();

    // ---- P4: mean + bias + sigmoid (block 0) ----
    if (b == 0) {
        for (int i = t; i < ngraphs; i += blockDim.x) {
            float m = sums[i] / fmaxf(cnt[i], 1.0f) + coeff[7];
            out[i] = 1.0f / (1.0f + expf(-m));
        }
    }
}

// ======================= fallback (R1 atomic path) =========================
__global__ void fb_coeffs_kernel(const float* __restrict__ W1, const float* __restrict__ b1,
                                 const float* __restrict__ W2, const float* __restrict__ b2,
                                 const float* __restrict__ W3, const float* __restrict__ b3,
                                 const float* __restrict__ lin_w, const float* __restrict__ lin_b,
                                 float* __restrict__ coeff,
                                 float* __restrict__ sums, float* __restrict__ cnt, int ngraphs) {
    for (int i = threadIdx.x; i < ngraphs; i += blockDim.x) { sums[i] = 0.f; cnt[i] = 0.f; }
    if (threadIdx.x == 0) {
        float w3l[16], w2l[16];
        for (int i = 0; i < 16; ++i) {
            float s = 0.f;
            for (int j = 0; j < 16; ++j) s += W3[i * 16 + j] * lin_w[j];
            w3l[i] = s;
        }
        for (int i = 0; i < 16; ++i) {
            float s = 0.f;
            for (int j = 0; j < 16; ++j) s += W2[i * 16 + j] * w3l[j];
            w2l[i] = s;
        }
        for (int i = 0; i < 4; ++i) {
            float s = 0.f;
            for (int j = 0; j < 16; ++j) s += W1[i * 16 + j] * w2l[j];
            coeff[i] = s;
        }
        float s2 = 0.f, s1 = 0.f, s0 = 0.f;
        for (int j = 0; j < 16; ++j) {
            s2 += b1[j] * w2l[j];
            s1 += b2[j] * w3l[j];
            s0 += b3[j] * lin_w[j];
        }
        coeff[4] = s2; coeff[5] = s1; coeff[6] = s0; coeff[7] = lin_b[0];
    }
}
__global__ void fb_init_kernel(float* __restrict__ deg, int n) {
    int i = blockIdx.x * blockDim.x + threadIdx.x;
    int stride = gridDim.x * blockDim.x;
    for (int k = i; k < n; k += stride) deg[k] = 1.0f;
}
__global__ void fb_deg_kernel(const int* __restrict__ col, float* __restrict__ deg, int E) {
    int i = blockIdx.x * blockDim.x + threadIdx.x;
    int stride = gridDim.x * blockDim.x;
    for (int k = i; k < E; k += stride) atomicAdd(&deg[col[k]], 1.0f);
}
__global__ void fb_node0_kernel(const float* __restrict__ x, const float* __restrict__ coeff,
                                float* __restrict__ deg_dinv, float* __restrict__ g,
                                float* __restrict__ acc, int n) {
    int i = blockIdx.x * blockDim.x + threadIdx.x;
    int stride = gridDim.x * blockDim.x;
    for (int k = i; k < n; k += stride) {
        float d = rsqrtf(deg_dinv[k]);
        deg_dinv[k] = d;
        float4 xv = ((const float4*)x)[k];
        float t0 = xv.x * coeff[0] + xv.y * coeff[1] + xv.z * coeff[2] + xv.w * coeff[3];
        g[k] = d * t0;
        acc[k] = 0.f;
    }
}
__global__ void fb_edge_kernel(const int* __restrict__ ei, const float* __restrict__ g,
                               float* __restrict__ acc, int E) {
    int i = blockIdx.x * blockDim.x + threadIdx.x;
    int stride = gridDim.x * blockDim.x;
    for (int k = i; k < E; k += stride) atomicAdd(&acc[ei[E + k]], g[ei[k]]);
}
__global__ void fb_node_kernel(const float* __restrict__ dinv, float* __restrict__ g,
                               float* __restrict__ acc, const float* __restrict__ coeff,
                               int sidx, int n) {
    int i = blockIdx.x * blockDim.x + threadIdx.x;
    int stride = gridDim.x * blockDim.x;
    for (int k = i; k < n; k += stride) {
        float d = dinv[k];
        float t = d * (acc[k] + g[k]) + coeff[sidx];
        g[k] = d * t;
        acc[k] = 0.f;
    }
}
__global__ void fb_pool_kernel(const float* __restrict__ dinv, const float* __restrict__ g,
                               const float* __restrict__ acc, const float* __restrict__ coeff,
                               const int* __restrict__ batch, float* __restrict__ sums,
                               float* __restrict__ cnt, int n) {
    int i = blockIdx.x * blockDim.x + threadIdx.x;
    int stride = gridDim.x * blockDim.x;
    for (int k = i; k < n; k += stride) {
        float d = dinv[k];
        float t3 = d * (acc[k] + g[k]) + coeff[6];
        int b = batch[k];
        atomicAdd(&sums[b], t3);
        atomicAdd(&cnt[b], 1.0f);
    }
}
__global__ void fb_final_kernel(const float* __restrict__ sums, const float* __restrict__ cnt,
                                const float* __restrict__ coeff, float* __restrict__ out,
                                int ngraphs) {
    int i = blockIdx.x * blockDim.x + threadIdx.x;
    if (i < ngraphs) {
        float m = sums[i] / fmaxf(cnt[i], 1.0f) + coeff[7];
        out[i] = 1.0f / (1.0f + expf(-m));
    }
}
// ===========================================================================

extern "C" void kernel_launch(void* const* d_in, const int* in_sizes, int n_in,
                              void* d_out, int out_size, void* d_ws, size_t ws_size,
                              hipStream_t stream) {
    const float* x     = (const float*)d_in[0];
    const int*   ei    = (const int*)d_in[1];
    const int*   batch = (const int*)d_in[2];
    const float* W1    = (const float*)d_in[3];
    const float* b1    = (const float*)d_in[4];
    const float* W2    = (const float*)d_in[5];
    const float* b2    = (const float*)d_in[6];
    const float* W3    = (const float*)d_in[7];
    const float* b3    = (const float*)d_in[8];
    const float* lin_w = (const float*)d_in[9];
    const float* lin_b = (const float*)d_in[10];

    const int n       = in_sizes[0] / 4;   // 100000
    const int E       = in_sizes[1] / 2;   // 3200000
    const int ngraphs = out_size;          // 1000

    const int nbuck = (n + BSZ - 1) / BSZ; // 391
    const int B = 256;

    size_t npad  = ((size_t)n + 255) & ~(size_t)255;
    size_t gpad  = ((size_t)ngraphs + 255) & ~(size_t)255;
    size_t nbpad = ((size_t)nbuck + 1 + 255) & ~(size_t)255;
    size_t mlen  = (size_t)NB_SCAT * nbuck;

    size_t need = (256 + 3 * mlen + 2 * nbpad + (size_t)E + 3 * npad + 2 * gpad) * 4;

    float* ws    = (float*)d_ws;
    float* coeff = ws;                                    // 256
    unsigned* Mcnt     = (unsigned*)(coeff + 256);        // mlen
    unsigned* Mloc     = Mcnt + mlen;                     // mlen
    unsigned* Mpre     = Mloc + mlen;                     // mlen
    unsigned* binTotal = Mpre + mlen;                     // nbpad
    unsigned* bstart   = binTotal + nbpad;                // nbpad
    unsigned* buck     = bstart + nbpad;                  // E (16B aligned)
    float* dinv  = (float*)(buck + E);                    // npad
    float* gA    = dinv + npad;                           // npad
    float* gB    = gA + npad;                             // npad
    float* sums  = gB + npad;                             // gpad
    float* cnt   = sums + gpad;                           // gpad

    int tile = (((E + NB_SCAT - 1) / NB_SCAT) + 3) & ~3;   // multiple of 4
    size_t ldsScat = (size_t)(4 * nbuck + B_SCAT + tile) * sizeof(unsigned);

    bool mainok = (n < (1 << 17)) && nbuck >= 1 && nbuck <= 512 &&
                  ws_size >= need && ldsScat <= 63 * 1024;

    if (!mainok) {
        // -------- fallback: R1 atomic path --------
        float* fcoeff = ws;
        float* deg = fcoeff + 256;
        float* g   = deg + npad;
        float* acc = g + npad;
        float* fsums = acc + npad;
        float* fcnt  = fsums + gpad;
        int nodeBlocks = (n + B - 1) / B;
        int edgeBlocks = (E + B - 1) / B;
        fb_coeffs_kernel<<<1, 64, 0, stream>>>(W1, b1, W2, b2, W3, b3, lin_w, lin_b, fcoeff,
                                               fsums, fcnt, ngraphs);
        fb_init_kernel<<<nodeBlocks, B, 0, stream>>>(deg, n);
        fb_deg_kernel<<<edgeBlocks, B, 0, stream>>>(ei + E, deg, E);
        fb_node0_kernel<<<nodeBlocks, B, 0, stream>>>(x, fcoeff, deg, g, acc, n);
        fb_edge_kernel<<<edgeBlocks, B, 0, stream>>>(ei, g, acc, E);
        fb_node_kernel<<<nodeBlocks, B, 0, stream>>>(deg, g, acc, fcoeff, 4, n);
        fb_edge_kernel<<<edgeBlocks, B, 0, stream>>>(ei, g, acc, E);
        fb_node_kernel<<<nodeBlocks, B, 0, stream>>>(deg, g, acc, fcoeff, 5, n);
        fb_edge_kernel<<<edgeBlocks, B, 0, stream>>>(ei, g, acc, E);
        fb_pool_kernel<<<nodeBlocks, B, 0, stream>>>(deg, g, acc, fcoeff, batch, fsums, fcnt, n);
        fb_final_kernel<<<(ngraphs + B - 1) / B, B, 0, stream>>>(fsums, fcnt, fcoeff, (float*)d_out, ngraphs);
        return;
    }

    size_t ldsHist = (size_t)nbuck * sizeof(unsigned);

    hist_kernel<<<NB_SCAT, B_SCAT, ldsHist, stream>>>(ei + E, E, tile, nbuck, Mcnt, Mloc,
                                                      W1, b1, W2, b2, W3, b3, lin_w, lin_b,
                                                      coeff, sums, cnt, ngraphs);
    scanA_kernel<<<nbuck, NB_SCAT, 0, stream>>>(Mcnt, Mpre, binTotal, nbuck);
    scatter_kernel<<<NB_SCAT, B_SCAT, ldsScat, stream>>>(ei, ei + E, E, tile, nbuck,
                                                         Mcnt, Mloc, Mpre, binTotal,
                                                         bstart, buck);

    float* outp = (float*)d_out;
    int n_ = n, nbuck_ = nbuck, ngraphs_ = ngraphs;
    void* args[] = { (void*)&buck, (void*)&bstart, (void*)&x, (void*)&coeff, (void*)&batch,
                     (void*)&dinv, (void*)&gA, (void*)&gB, (void*)&sums, (void*)&cnt,
                     (void*)&outp, (void*)&n_, (void*)&nbuck_, (void*)&ngraphs_ };
    hipLaunchCooperativeKernel((void*)mega_kernel, dim3(nbuck), dim3(B_MEGA),
                               args, 0, stream);
}

// Round 11
// 127.984 us; speedup vs baseline: 2.2685x; 2.2685x over previous
//
#include <hip/hip_runtime.h>
#include <math.h>

// ---------------------------------------------------------------------------
// GCN: 3x GCNConv (linear) -> mean pool -> linear -> sigmoid.
// Linear-collapse identity (absmax 0.0 through R10):
//   h3 @ lin_w = A(A(A(X u) + s2) + s1) + s0,  u = W1W2W3 lin_w.
// R10 lesson: cooperative grid.sync() costs ~50us/sync on MI355X (cross-XCD
// atomic barrier with 400K pollers) -> mega-kernel 256us vs ~60us of work.
// R11: back to R9's 8 separate dispatches (1.6us/boundary), keeping R10's
// scatter table-hoist (hist emits Mcnt+Mloc; scanA emits Mpre+binTotal;
// scatter only loads tables -> no redundant 12.8MB pass).
// ---------------------------------------------------------------------------

#define SHIFT      8
#define BSZ        256         // nodes per bucket = 1<<SHIFT
#define NB_SCAT    256         // blocks for hist/scatter phases
#define B_SCAT     1024        // threads for hist/scatter
#define B_GATH     1024        // threads for bucket (gather) kernels
#define ROWMASK    0x1FFFFu    // 17 bits for row id (n < 131072)
#define PSLOTS     64          // LDS pool slots per pass-3 block
#define MAXNB      2048        // scan capacity guard

// ---- K1: histogram + in-block scan (Mcnt, Mloc) + coeffs + zero sums ----
__global__ void hist_kernel(const int* __restrict__ col, int E, int tile, int nbuck,
                            unsigned* __restrict__ Mcnt, unsigned* __restrict__ Mloc,
                            const float* __restrict__ W1, const float* __restrict__ b1,
                            const float* __restrict__ W2, const float* __restrict__ b2,
                            const float* __restrict__ W3, const float* __restrict__ b3,
                            const float* __restrict__ lin_w, const float* __restrict__ lin_b,
                            float* __restrict__ coeff,
                            float* __restrict__ sums, float* __restrict__ cnt, int ngraphs) {
    extern __shared__ unsigned h[];
    __shared__ unsigned tsum[B_SCAT];
    __shared__ float w3l[16], w2l[16];
    int t = threadIdx.x;
    for (int i = t; i < nbuck; i += blockDim.x) h[i] = 0;
    if (blockIdx.x == 0) {
        for (int i = t; i < ngraphs; i += blockDim.x) { sums[i] = 0.f; cnt[i] = 0.f; }
        if (t < 16) {
            float s = 0.f;
            for (int j = 0; j < 16; ++j) s += W3[t * 16 + j] * lin_w[j];
            w3l[t] = s;
        }
    }
    __syncthreads();
    if (blockIdx.x == 0 && t < 16) {
        float s = 0.f;
        for (int j = 0; j < 16; ++j) s += W2[t * 16 + j] * w3l[j];
        w2l[t] = s;
    }
    __syncthreads();
    if (blockIdx.x == 0) {
        if (t < 4) {
            float s = 0.f;
            for (int j = 0; j < 16; ++j) s += W1[t * 16 + j] * w2l[j];
            coeff[t] = s;
        } else if (t == 4) {
            float s = 0.f;
            for (int j = 0; j < 16; ++j) s += b1[j] * w2l[j];
            coeff[4] = s;
        } else if (t == 5) {
            float s = 0.f;
            for (int j = 0; j < 16; ++j) s += b2[j] * w3l[j];
            coeff[5] = s;
        } else if (t == 6) {
            float s = 0.f;
            for (int j = 0; j < 16; ++j) s += b3[j] * lin_w[j];
            coeff[6] = s;
        } else if (t == 7) {
            coeff[7] = lin_b[0];
        }
    }
    // histogram of this block's tile
    int b = blockIdx.x;
    int s = b * tile, e = min(s + tile, E);          // s multiple of 4
    if (s < e) {
        int nq = (e - s) >> 2;
        const int4* c4 = (const int4*)(col + s);
        for (int q = t; q < nq; q += blockDim.x) {
            int4 c = c4[q];
            atomicAdd(&h[((unsigned)c.x) >> SHIFT], 1u);
            atomicAdd(&h[((unsigned)c.y) >> SHIFT], 1u);
            atomicAdd(&h[((unsigned)c.z) >> SHIFT], 1u);
            atomicAdd(&h[((unsigned)c.w) >> SHIFT], 1u);
        }
        for (int k = s + (nq << 2) + t; k < e; k += blockDim.x)
            atomicAdd(&h[((unsigned)col[k]) >> SHIFT], 1u);
    }
    __syncthreads();
    // in-block exclusive scan of h -> Mloc; counts -> Mcnt
    const int C = MAXNB / B_SCAT;            // 2 elems/thread
    unsigned lv[C];
    unsigned run = 0;
    for (int k = 0; k < C; ++k) {
        int i = t * C + k;
        unsigned x = (i < nbuck) ? h[i] : 0u;
        lv[k] = run; run += x;
    }
    tsum[t] = run;
    __syncthreads();
    for (int off = 1; off < B_SCAT; off <<= 1) {
        unsigned u = (t >= off) ? tsum[t - off] : 0u;
        __syncthreads();
        tsum[t] += u;
        __syncthreads();
    }
    unsigned ex = (t == 0) ? 0u : tsum[t - 1];
    for (int k = 0; k < C; ++k) {
        int i = t * C + k;
        if (i < nbuck) {
            Mcnt[(size_t)b * nbuck + i] = h[i];
            Mloc[(size_t)b * nbuck + i] = ex + lv[k];
        }
    }
}

// ---- K2: per-bin exclusive scan over block counts -> Mpre, binTotal ----
__global__ void scanA_kernel(const unsigned* __restrict__ Mcnt, unsigned* __restrict__ Mpre,
                             unsigned* __restrict__ binTotal, int nbuck) {
    __shared__ unsigned sc[NB_SCAT];
    int b = blockIdx.x;
    int t = threadIdx.x;
    unsigned v = Mcnt[(size_t)t * nbuck + b];
    sc[t] = v;
    __syncthreads();
    for (int off = 1; off < NB_SCAT; off <<= 1) {
        unsigned u = (t >= off) ? sc[t - off] : 0u;
        __syncthreads();
        sc[t] += u;
        __syncthreads();
    }
    Mpre[(size_t)t * nbuck + b] = sc[t] - v;     // exclusive within bin
    if (t == NB_SCAT - 1) binTotal[b] = sc[t];
}

// ---- K3: scatter; tables preloaded, only binTotal scan in-block ----
// pack: row(17b) | col_low(8b)<<17
__global__ void scatter_kernel(const int* __restrict__ row, const int* __restrict__ col,
                               int E, int tile, int nbuck,
                               const unsigned* __restrict__ Mcnt,
                               const unsigned* __restrict__ Mloc,
                               const unsigned* __restrict__ Mpre,
                               const unsigned* __restrict__ binTotal,
                               unsigned* __restrict__ bstart,
                               unsigned* __restrict__ out) {
    extern __shared__ unsigned lds[];
    unsigned* hA    = lds;                   // nbuck  local counts
    unsigned* lofs  = lds + nbuck;           // nbuck  local exclusive offsets
    unsigned* lcur  = lds + 2 * nbuck;       // nbuck  placement cursors
    unsigned* gbase = lds + 3 * nbuck;       // nbuck  global run starts (this block)
    unsigned* tsum  = lds + 4 * nbuck;       // B_SCAT scan workspace
    unsigned* stage = lds + 4 * nbuck + B_SCAT; // tile staged packed words
    int t = threadIdx.x, j = blockIdx.x;
    // load local tables
    for (int i = t; i < nbuck; i += blockDim.x) {
        unsigned c = Mcnt[(size_t)j * nbuck + i];
        unsigned l = Mloc[(size_t)j * nbuck + i];
        hA[i] = c; lofs[i] = l; lcur[i] = l;
    }
    // binTotal exclusive scan -> gbase (+ bstart publish from block 0)
    const int C = MAXNB / B_SCAT;            // 2 elems/thread
    unsigned lv[C];
    unsigned run = 0;
    for (int k = 0; k < C; ++k) {
        int i = t * C + k;
        unsigned x = (i < nbuck) ? binTotal[i] : 0u;
        lv[k] = run; run += x;
    }
    tsum[t] = run;
    __syncthreads();
    for (int off = 1; off < B_SCAT; off <<= 1) {
        unsigned u = (t >= off) ? tsum[t - off] : 0u;
        __syncthreads();
        tsum[t] += u;
        __syncthreads();
    }
    unsigned ex = (t == 0) ? 0u : tsum[t - 1];
    for (int k = 0; k < C; ++k) {
        int i = t * C + k;
        if (i < nbuck) {
            unsigned bb = ex + lv[k];
            gbase[i] = bb + Mpre[(size_t)j * nbuck + i];
            if (j == 0) bstart[i] = bb;
        }
    }
    if (j == 0 && t == 0) bstart[nbuck] = (unsigned)E;
    __syncthreads();
    // placement into stage (LDS random write)
    int s = j * tile, e = min(s + tile, E);
    if (s < e) {
        int nq = (e - s) >> 2;
        const int4* r4 = (const int4*)(row + s);
        const int4* c4 = (const int4*)(col + s);
        for (int q = t; q < nq; q += blockDim.x) {
            int4 r = r4[q];
            int4 c = c4[q];
            unsigned p0 = atomicAdd(&lcur[((unsigned)c.x) >> SHIFT], 1u);
            unsigned p1 = atomicAdd(&lcur[((unsigned)c.y) >> SHIFT], 1u);
            unsigned p2 = atomicAdd(&lcur[((unsigned)c.z) >> SHIFT], 1u);
            unsigned p3 = atomicAdd(&lcur[((unsigned)c.w) >> SHIFT], 1u);
            stage[p0] = (unsigned)r.x | (((unsigned)c.x & (BSZ - 1)) << 17);
            stage[p1] = (unsigned)r.y | (((unsigned)c.y & (BSZ - 1)) << 17);
            stage[p2] = (unsigned)r.z | (((unsigned)c.z & (BSZ - 1)) << 17);
            stage[p3] = (unsigned)r.w | (((unsigned)c.w & (BSZ - 1)) << 17);
        }
        for (int k = s + (nq << 2) + t; k < e; k += blockDim.x) {
            unsigned c = (unsigned)col[k];
            unsigned pos = atomicAdd(&lcur[c >> SHIFT], 1u);
            stage[pos] = (unsigned)row[k] | ((c & (BSZ - 1)) << 17);
        }
    }
    __syncthreads();
    // flush: per wave per bucket, consecutive lanes -> consecutive addresses
    int wid = t >> 6, lane = t & 63, nw = blockDim.x >> 6;
    for (int b = wid; b < nbuck; b += nw) {
        unsigned cntb = hA[b], lo = lofs[b], go = gbase[b];
        for (unsigned i = lane; i < cntb; i += 64)
            out[go + i] = stage[lo + i];
    }
}

// ---- K4: degree count + node0 epilogue (dinv, g0 = dinv * x.u) ----
__global__ void degnode0_kernel(const unsigned* __restrict__ buck,
                                const unsigned* __restrict__ bstart,
                                const float* __restrict__ x, const float* __restrict__ coeff,
                                float* __restrict__ dinv, float* __restrict__ g, int n) {
    __shared__ float acc[BSZ];
    int b = blockIdx.x;
    if (threadIdx.x < BSZ) acc[threadIdx.x] = 0.f;
    __syncthreads();
    unsigned s = bstart[b], e = bstart[b + 1];
    unsigned sa = (s + 3u) & ~3u;
    if (sa > e) sa = e;
    if (s + threadIdx.x < sa)
        atomicAdd(&acc[buck[s + threadIdx.x] >> 17], 1.0f);
    unsigned nq = (e - sa) >> 2;
    const uint4* bq = (const uint4*)(buck + sa);
    for (unsigned q = threadIdx.x; q < nq; q += blockDim.x) {
        uint4 w = bq[q];
        atomicAdd(&acc[w.x >> 17], 1.0f);
        atomicAdd(&acc[w.y >> 17], 1.0f);
        atomicAdd(&acc[w.z >> 17], 1.0f);
        atomicAdd(&acc[w.w >> 17], 1.0f);
    }
    for (unsigned k = sa + (nq << 2) + threadIdx.x; k < e; k += blockDim.x)
        atomicAdd(&acc[buck[k] >> 17], 1.0f);
    __syncthreads();
    int node = b * BSZ + threadIdx.x;
    if (threadIdx.x < BSZ && node < n) {
        float d = rsqrtf(acc[threadIdx.x] + 1.0f);
        dinv[node] = d;
        float4 xv = ((const float4*)x)[node];
        float t0 = xv.x * coeff[0] + xv.y * coeff[1] + xv.z * coeff[2] + xv.w * coeff[3];
        g[node] = d * t0;
    }
}

// ---- K5/K6: gather pass with fused node epilogue ----
__global__ void gather_kernel(const unsigned* __restrict__ buck,
                              const unsigned* __restrict__ bstart,
                              const float* __restrict__ dinv, const float* __restrict__ gin,
                              float* __restrict__ gout, const float* __restrict__ coeff,
                              int sidx, int n) {
    __shared__ float acc[BSZ];
    int b = blockIdx.x;
    if (threadIdx.x < BSZ) acc[threadIdx.x] = 0.f;
    __syncthreads();
    unsigned s = bstart[b], e = bstart[b + 1];
    unsigned sa = (s + 3u) & ~3u;
    if (sa > e) sa = e;
    if (s + threadIdx.x < sa) {
        unsigned w = buck[s + threadIdx.x];
        atomicAdd(&acc[w >> 17], gin[w & ROWMASK]);
    }
    unsigned nq = (e - sa) >> 2;
    const uint4* bq = (const uint4*)(buck + sa);
    for (unsigned q = threadIdx.x; q < nq; q += blockDim.x) {
        uint4 w = bq[q];
        float a0 = gin[w.x & ROWMASK];
        float a1 = gin[w.y & ROWMASK];
        float a2 = gin[w.z & ROWMASK];
        float a3 = gin[w.w & ROWMASK];
        atomicAdd(&acc[w.x >> 17], a0);
        atomicAdd(&acc[w.y >> 17], a1);
        atomicAdd(&acc[w.z >> 17], a2);
        atomicAdd(&acc[w.w >> 17], a3);
    }
    for (unsigned k = sa + (nq << 2) + threadIdx.x; k < e; k += blockDim.x) {
        unsigned w = buck[k];
        atomicAdd(&acc[w >> 17], gin[w & ROWMASK]);
    }
    __syncthreads();
    int node = b * BSZ + threadIdx.x;
    if (threadIdx.x < BSZ && node < n) {
        float d = dinv[node];
        float t = d * (acc[threadIdx.x] + gin[node]) + coeff[sidx];
        gout[node] = d * t;
    }
}

// ---- K7: pass 3 gather + fused segmented mean-pool (batch sorted) ----
__global__ void gatherpool_kernel(const unsigned* __restrict__ buck,
                                  const unsigned* __restrict__ bstart,
                                  const float* __restrict__ dinv, const float* __restrict__ gin,
                                  const float* __restrict__ coeff, const int* __restrict__ batch,
                                  float* __restrict__ sums, float* __restrict__ cnt, int n) {
    __shared__ float acc[BSZ];
    __shared__ float ls[PSLOTS], lc[PSLOTS];
    __shared__ int bF;
    int b = blockIdx.x;
    if (threadIdx.x < BSZ) acc[threadIdx.x] = 0.f;
    for (int i = threadIdx.x; i < PSLOTS; i += blockDim.x) { ls[i] = 0.f; lc[i] = 0.f; }
    if (threadIdx.x == 0) bF = batch[min(b * BSZ, n - 1)];
    __syncthreads();
    unsigned s = bstart[b], e = bstart[b + 1];
    unsigned sa = (s + 3u) & ~3u;
    if (sa > e) sa = e;
    if (s + threadIdx.x < sa) {
        unsigned w = buck[s + threadIdx.x];
        atomicAdd(&acc[w >> 17], gin[w & ROWMASK]);
    }
    unsigned nq = (e - sa) >> 2;
    const uint4* bq = (const uint4*)(buck + sa);
    for (unsigned q = threadIdx.x; q < nq; q += blockDim.x) {
        uint4 w = bq[q];
        float a0 = gin[w.x & ROWMASK];
        float a1 = gin[w.y & ROWMASK];
        float a2 = gin[w.z & ROWMASK];
        float a3 = gin[w.w & ROWMASK];
        atomicAdd(&acc[w.x >> 17], a0);
        atomicAdd(&acc[w.y >> 17], a1);
        atomicAdd(&acc[w.z >> 17], a2);
        atomicAdd(&acc[w.w >> 17], a3);
    }
    for (unsigned k = sa + (nq << 2) + threadIdx.x; k < e; k += blockDim.x) {
        unsigned w = buck[k];
        atomicAdd(&acc[w >> 17], gin[w & ROWMASK]);
    }
    __syncthreads();
    int node = b * BSZ + threadIdx.x;
    if (threadIdx.x < BSZ && node < n) {
        float d = dinv[node];
        float t3 = d * (acc[threadIdx.x] + gin[node]) + coeff[6];
        int rb = batch[node] - bF;               // batch sorted -> rb >= 0
        if (rb < PSLOTS) {
            atomicAdd(&ls[rb], t3);
            atomicAdd(&lc[rb], 1.0f);
        } else {
            atomicAdd(&sums[bF + rb], t3);
            atomicAdd(&cnt[bF + rb], 1.0f);
        }
    }
    __syncthreads();
    for (int i = threadIdx.x; i < PSLOTS; i += blockDim.x) {
        if (lc[i] != 0.f) {
            atomicAdd(&sums[bF + i], ls[i]);
            atomicAdd(&cnt[bF + i], lc[i]);
        }
    }
}

// ---- K8: mean + linear bias + sigmoid ----
__global__ void final_kernel(const float* __restrict__ sums, const float* __restrict__ cnt,
                             const float* __restrict__ coeff, float* __restrict__ out,
                             int ngraphs) {
    int i = blockIdx.x * blockDim.x + threadIdx.x;
    if (i < ngraphs) {
        float m = sums[i] / fmaxf(cnt[i], 1.0f) + coeff[7];
        out[i] = 1.0f / (1.0f + expf(-m));
    }
}

// ======================= fallback (R1 atomic path) =========================
__global__ void fb_coeffs_kernel(const float* __restrict__ W1, const float* __restrict__ b1,
                                 const float* __restrict__ W2, const float* __restrict__ b2,
                                 const float* __restrict__ W3, const float* __restrict__ b3,
                                 const float* __restrict__ lin_w, const float* __restrict__ lin_b,
                                 float* __restrict__ coeff,
                                 float* __restrict__ sums, float* __restrict__ cnt, int ngraphs) {
    for (int i = threadIdx.x; i < ngraphs; i += blockDim.x) { sums[i] = 0.f; cnt[i] = 0.f; }
    if (threadIdx.x == 0) {
        float w3l[16], w2l[16];
        for (int i = 0; i < 16; ++i) {
            float s = 0.f;
            for (int j = 0; j < 16; ++j) s += W3[i * 16 + j] * lin_w[j];
            w3l[i] = s;
        }
        for (int i = 0; i < 16; ++i) {
            float s = 0.f;
            for (int j = 0; j < 16; ++j) s += W2[i * 16 + j] * w3l[j];
            w2l[i] = s;
        }
        for (int i = 0; i < 4; ++i) {
            float s = 0.f;
            for (int j = 0; j < 16; ++j) s += W1[i * 16 + j] * w2l[j];
            coeff[i] = s;
        }
        float s2 = 0.f, s1 = 0.f, s0 = 0.f;
        for (int j = 0; j < 16; ++j) {
            s2 += b1[j] * w2l[j];
            s1 += b2[j] * w3l[j];
            s0 += b3[j] * lin_w[j];
        }
        coeff[4] = s2; coeff[5] = s1; coeff[6] = s0; coeff[7] = lin_b[0];
    }
}
__global__ void fb_init_kernel(float* __restrict__ deg, int n) {
    int i = blockIdx.x * blockDim.x + threadIdx.x;
    int stride = gridDim.x * blockDim.x;
    for (int k = i; k < n; k += stride) deg[k] = 1.0f;
}
__global__ void fb_deg_kernel(const int* __restrict__ col, float* __restrict__ deg, int E) {
    int i = blockIdx.x * blockDim.x + threadIdx.x;
    int stride = gridDim.x * blockDim.x;
    for (int k = i; k < E; k += stride) atomicAdd(&deg[col[k]], 1.0f);
}
__global__ void fb_node0_kernel(const float* __restrict__ x, const float* __restrict__ coeff,
                                float* __restrict__ deg_dinv, float* __restrict__ g,
                                float* __restrict__ acc, int n) {
    int i = blockIdx.x * blockDim.x + threadIdx.x;
    int stride = gridDim.x * blockDim.x;
    for (int k = i; k < n; k += stride) {
        float d = rsqrtf(deg_dinv[k]);
        deg_dinv[k] = d;
        float4 xv = ((const float4*)x)[k];
        float t0 = xv.x * coeff[0] + xv.y * coeff[1] + xv.z * coeff[2] + xv.w * coeff[3];
        g[k] = d * t0;
        acc[k] = 0.f;
    }
}
__global__ void fb_edge_kernel(const int* __restrict__ ei, const float* __restrict__ g,
                               float* __restrict__ acc, int E) {
    int i = blockIdx.x * blockDim.x + threadIdx.x;
    int stride = gridDim.x * blockDim.x;
    for (int k = i; k < E; k += stride) atomicAdd(&acc[ei[E + k]], g[ei[k]]);
}
__global__ void fb_node_kernel(const float* __restrict__ dinv, float* __restrict__ g,
                               float* __restrict__ acc, const float* __restrict__ coeff,
                               int sidx, int n) {
    int i = blockIdx.x * blockDim.x + threadIdx.x;
    int stride = gridDim.x * blockDim.x;
    for (int k = i; k < n; k += stride) {
        float d = dinv[k];
        float t = d * (acc[k] + g[k]) + coeff[sidx];
        g[k] = d * t;
        acc[k] = 0.f;
    }
}
__global__ void fb_pool_kernel(const float* __restrict__ dinv, const float* __restrict__ g,
                               const float* __restrict__ acc, const float* __restrict__ coeff,
                               const int* __restrict__ batch, float* __restrict__ sums,
                               float* __restrict__ cnt, int n) {
    int i = blockIdx.x * blockDim.x + threadIdx.x;
    int stride = gridDim.x * blockDim.x;
    for (int k = i; k < n; k += stride) {
        float d = dinv[k];
        float t3 = d * (acc[k] + g[k]) + coeff[6];
        int b = batch[k];
        atomicAdd(&sums[b], t3);
        atomicAdd(&cnt[b], 1.0f);
    }
}
// ===========================================================================

extern "C" void kernel_launch(void* const* d_in, const int* in_sizes, int n_in,
                              void* d_out, int out_size, void* d_ws, size_t ws_size,
                              hipStream_t stream) {
    const float* x     = (const float*)d_in[0];
    const int*   ei    = (const int*)d_in[1];
    const int*   batch = (const int*)d_in[2];
    const float* W1    = (const float*)d_in[3];
    const float* b1    = (const float*)d_in[4];
    const float* W2    = (const float*)d_in[5];
    const float* b2    = (const float*)d_in[6];
    const float* W3    = (const float*)d_in[7];
    const float* b3    = (const float*)d_in[8];
    const float* lin_w = (const float*)d_in[9];
    const float* lin_b = (const float*)d_in[10];

    const int n       = in_sizes[0] / 4;   // 100000
    const int E       = in_sizes[1] / 2;   // 3200000
    const int ngraphs = out_size;          // 1000

    const int nbuck = (n + BSZ - 1) / BSZ; // 391
    const int B = 256;

    size_t npad  = ((size_t)n + 255) & ~(size_t)255;
    size_t gpad  = ((size_t)ngraphs + 255) & ~(size_t)255;
    size_t nbpad = ((size_t)nbuck + 1 + 255) & ~(size_t)255;
    size_t mlen  = (size_t)NB_SCAT * nbuck;

    size_t need = (256 + 3 * mlen + 2 * nbpad + (size_t)E + 3 * npad + 2 * gpad) * 4;

    float* ws    = (float*)d_ws;
    float* coeff = ws;                                    // 256
    unsigned* Mcnt     = (unsigned*)(coeff + 256);        // mlen
    unsigned* Mloc     = Mcnt + mlen;                     // mlen
    unsigned* Mpre     = Mloc + mlen;                     // mlen
    unsigned* binTotal = Mpre + mlen;                     // nbpad
    unsigned* bstart   = binTotal + nbpad;                // nbpad
    unsigned* buck     = bstart + nbpad;                  // E (16B aligned)
    float* dinv  = (float*)(buck + E);                    // npad
    float* gA    = dinv + npad;                           // npad
    float* gB    = gA + npad;                             // npad
    float* sums  = gB + npad;                             // gpad
    float* cnt   = sums + gpad;                           // gpad

    int tile = (((E + NB_SCAT - 1) / NB_SCAT) + 3) & ~3;   // multiple of 4
    size_t ldsScat = (size_t)(4 * nbuck + B_SCAT + tile) * sizeof(unsigned);

    bool mainok = (n < (1 << 17)) && nbuck >= 1 && nbuck <= MAXNB &&
                  ws_size >= need && ldsScat <= 63 * 1024;

    if (!mainok) {
        // -------- fallback: R1 atomic path --------
        float* fcoeff = ws;
        float* deg = fcoeff + 256;
        float* g   = deg + npad;
        float* acc = g + npad;
        float* fsums = acc + npad;
        float* fcnt  = fsums + gpad;
        int nodeBlocks = (n + B - 1) / B;
        int edgeBlocks = (E + B - 1) / B;
        fb_coeffs_kernel<<<1, 64, 0, stream>>>(W1, b1, W2, b2, W3, b3, lin_w, lin_b, fcoeff,
                                               fsums, fcnt, ngraphs);
        fb_init_kernel<<<nodeBlocks, B, 0, stream>>>(deg, n);
        fb_deg_kernel<<<edgeBlocks, B, 0, stream>>>(ei + E, deg, E);
        fb_node0_kernel<<<nodeBlocks, B, 0, stream>>>(x, fcoeff, deg, g, acc, n);
        fb_edge_kernel<<<edgeBlocks, B, 0, stream>>>(ei, g, acc, E);
        fb_node_kernel<<<nodeBlocks, B, 0, stream>>>(deg, g, acc, fcoeff, 4, n);
        fb_edge_kernel<<<edgeBlocks, B, 0, stream>>>(ei, g, acc, E);
        fb_node_kernel<<<nodeBlocks, B, 0, stream>>>(deg, g, acc, fcoeff, 5, n);
        fb_edge_kernel<<<edgeBlocks, B, 0, stream>>>(ei, g, acc, E);
        fb_pool_kernel<<<nodeBlocks, B, 0, stream>>>(deg, g, acc, fcoeff, batch, fsums, fcnt, n);
        final_kernel<<<(ngraphs + B - 1) / B, B, 0, stream>>>(fsums, fcnt, fcoeff, (float*)d_out, ngraphs);
        return;
    }

    size_t ldsHist = (size_t)nbuck * sizeof(unsigned);

    hist_kernel<<<NB_SCAT, B_SCAT, ldsHist, stream>>>(ei + E, E, tile, nbuck, Mcnt, Mloc,
                                                      W1, b1, W2, b2, W3, b3, lin_w, lin_b,
                                                      coeff, sums, cnt, ngraphs);
    scanA_kernel<<<nbuck, NB_SCAT, 0, stream>>>(Mcnt, Mpre, binTotal, nbuck);
    scatter_kernel<<<NB_SCAT, B_SCAT, ldsScat, stream>>>(ei, ei + E, E, tile, nbuck,
                                                         Mcnt, Mloc, Mpre, binTotal,
                                                         bstart, buck);

    degnode0_kernel<<<nbuck, B_GATH, 0, stream>>>(buck, bstart, x, coeff, dinv, gA, n);
    gather_kernel<<<nbuck, B_GATH, 0, stream>>>(buck, bstart, dinv, gA, gB, coeff, 4, n);
    gather_kernel<<<nbuck, B_GATH, 0, stream>>>(buck, bstart, dinv, gB, gA, coeff, 5, n);
    gatherpool_kernel<<<nbuck, B_GATH, 0, stream>>>(buck, bstart, dinv, gA, coeff, batch,
                                                    sums, cnt, n);

    final_kernel<<<(ngraphs + B - 1) / B, B, 0, stream>>>(sums, cnt, coeff, (float*)d_out, ngraphs);
}